// Round 6
// baseline (334.692 us; speedup 1.0000x reference)
//
#include <hip/hip_runtime.h>

typedef __bf16 bf16;
typedef __bf16 bf16x2 __attribute__((ext_vector_type(2)));
typedef __bf16 bf16x4 __attribute__((ext_vector_type(4)));
typedef __bf16 bf16x8 __attribute__((ext_vector_type(8)));
typedef float floatx4 __attribute__((ext_vector_type(4)));

#define DD 768
#define NH 12
#define HDIM 64
#define BB 16
#define NN 1024
#define MTOT (BB*NN)   // 16384
#define WELEM (DD*DD)  // 589824

// Pipelined-GEMM LDS geometry: one K-tile buffer = A(256x64) + B(128x64) bf16
#define ABUF 16384
#define BBUF 8192
#define TBUF (ABUF + BBUF)   // 24576 bf16 = 48KB; 3 buffers = 144KB

__device__ __forceinline__ void async_cp16(const void* g, void* l) {
  __builtin_amdgcn_global_load_lds((const __attribute__((address_space(1))) void*)g,
                                   (__attribute__((address_space(3))) void*)l, 16, 0, 0);
}

// ---- prep: LN (blocks 0..4095), weight conv (4096..6975), sincos (6976..7231)
// sincos table built TRANSPOSED: tabs[j*1024 + n] = cos(rope[n][j]), second
// 64K-f32 half = sin. Coalesced consumption in the rope-fused GEMM epilogue.
__global__ __launch_bounds__(256) void prep_kernel(
    const float* __restrict__ x, const float* __restrict__ lnw,
    const float* __restrict__ lnb, bf16* __restrict__ A,
    const float* __restrict__ w0, const float* __restrict__ w1,
    const float* __restrict__ w2, const float* __restrict__ w3,
    const float* __restrict__ w4, bf16* __restrict__ Wb,
    const float* __restrict__ rope, float* __restrict__ tabs) {
  int blk = blockIdx.x;
  int tid = threadIdx.x;
  if (blk < 4096) {
    // ---------------- LayerNorm: x (f32) -> A (bf16) ----------------
    int row = blk * 4 + (tid >> 6);
    int lane = tid & 63;
    const float4* xr = (const float4*)(x + (size_t)row * DD);
    float4 v[3];
    float s = 0.f;
#pragma unroll
    for (int i = 0; i < 3; i++) {
      v[i] = xr[lane + 64 * i];
      s += v[i].x + v[i].y + v[i].z + v[i].w;
    }
#pragma unroll
    for (int o = 32; o; o >>= 1) s += __shfl_xor(s, o);
    float mu = s * (1.f / 768.f);
    float vs = 0.f;
#pragma unroll
    for (int i = 0; i < 3; i++) {
      float dx;
      dx = v[i].x - mu; vs += dx * dx;
      dx = v[i].y - mu; vs += dx * dx;
      dx = v[i].z - mu; vs += dx * dx;
      dx = v[i].w - mu; vs += dx * dx;
    }
#pragma unroll
    for (int o = 32; o; o >>= 1) vs += __shfl_xor(vs, o);
    float rstd = rsqrtf(vs * (1.f / 768.f) + 1e-5f);
    const float4* wv = (const float4*)lnw;
    const float4* bv = (const float4*)lnb;
    bf16* Ar = A + (size_t)row * DD;
#pragma unroll
    for (int i = 0; i < 3; i++) {
      int c4 = lane + 64 * i;
      float4 ww = wv[c4], bb = bv[c4];
      bf16x4 pk;
      pk[0] = (bf16)((v[i].x - mu) * rstd * ww.x + bb.x);
      pk[1] = (bf16)((v[i].y - mu) * rstd * ww.y + bb.y);
      pk[2] = (bf16)((v[i].z - mu) * rstd * ww.z + bb.z);
      pk[3] = (bf16)((v[i].w - mu) * rstd * ww.w + bb.w);
      *(bf16x4*)(Ar + c4 * 4) = pk;
    }
  } else if (blk < 4096 + 2880) {
    // ------- Weights f32 -> bf16, order: enc, gate, qk, v, out -------
    int i = (blk - 4096) * 256 + tid;
    int which = i / (WELEM / 4);
    int off = (i % (WELEM / 4)) * 4;
    const float* s = which == 0 ? w0 : which == 1 ? w1 : which == 2 ? w2 : which == 3 ? w3 : w4;
    float4 v = *(const float4*)(s + off);
    bf16x4 pk;
    pk[0] = (bf16)v.x; pk[1] = (bf16)v.y; pk[2] = (bf16)v.z; pk[3] = (bf16)v.w;
    *(bf16x4*)(Wb + (size_t)i * 4) = pk;
  } else {
    // ---- sincos table TRANSPOSED: i = j*1024 + n; angle = rope[n*64+j] ----
    int i = (blk - 6976) * 256 + tid;
    int j = i >> 10, n = i & 1023;
    float a = rope[n * 64 + j];
    float s, c;
    __sincosf(a, &s, &c);
    tabs[i] = c;
    tabs[65536 + i] = s;
  }
}

// ============================================================================
// Pipelined GEMM: 256x128 block tile, 8 waves, 64x64/wave, BK=64,
// triple-buffered LDS, prefetch distance 2, counted vmcnt(6).
// EPI: 0 relu->bf16, 1 plain->bf16, 2 transposed (B,H,HD,N)->bf16,
//      3 sigmoid->bf16, 4 final f32, 5 rope-fused dual write (QKr + QKrT,
//      QKrT staged through LDS; cos/sin from transposed table, coalesced).
// EPI != 2: MFMA operands swapped (computes C^T) -> packed row-major stores.
// ============================================================================
template<int EPI>
__device__ __forceinline__ void gemm_body(
    int bm, int bn, int bnl,
    const bf16* __restrict__ Aop, const bf16* __restrict__ W,
    const float* __restrict__ bias,
    bf16* __restrict__ Cb, bf16* __restrict__ CT, float* __restrict__ Cf,
    const float* __restrict__ Xres, const bf16* __restrict__ Gate,
    const float* __restrict__ tabs, bf16* smem) {
  int tid = threadIdx.x;
  int w = tid >> 6, lane = tid & 63;
  int quad = lane >> 4, l16 = lane & 15;
  int wm = w >> 1, wn = w & 1;          // 4M x 2N wave grid -> 64x64 per wave
  int sr = lane >> 3;                   // row within 8-row chunk
  int scg = (lane & 7) ^ sr;            // pre-swizzled source colgroup
  int swz = l16 & 7;

  const bf16* Ag = Aop + (size_t)(bm * 256) * DD;
  const bf16* Bg = W + (size_t)(bn * 128) * DD;
  const bf16* srcA = Ag + (size_t)(w * 8 + sr) * DD + scg * 8;
  const bf16* srcB = Bg + (size_t)(w * 8 + sr) * DD + scg * 8;

  floatx4 acc[4][4];
#pragma unroll
  for (int i = 0; i < 4; i++)
#pragma unroll
    for (int j = 0; j < 4; j++)
      acc[i][j] = (floatx4){0.f, 0.f, 0.f, 0.f};

  // 6 global_load_lds per wave per K-tile, split in two 3-load halves
  auto stageH0 = [&](int k0, bf16* buf) {
    async_cp16(srcA + (size_t)0 * (64 * DD) + k0, buf + (w + 0) * 512);
    async_cp16(srcA + (size_t)1 * (64 * DD) + k0, buf + (w + 8) * 512);
    async_cp16(srcB + k0, buf + ABUF + w * 512);
  };
  auto stageH1 = [&](int k0, bf16* buf) {
    async_cp16(srcA + (size_t)2 * (64 * DD) + k0, buf + (w + 16) * 512);
    async_cp16(srcA + (size_t)3 * (64 * DD) + k0, buf + (w + 24) * 512);
    async_cp16(srcB + (size_t)64 * DD + k0, buf + ABUF + (w + 8) * 512);
  };

  // prologue: tiles 0 and 1 in flight (12 outstanding vmcnt events/wave)
  stageH0(0, smem);               stageH1(0, smem);
  stageH0(64, smem + TBUF);       stageH1(64, smem + TBUF);

#pragma unroll
  for (int t = 0; t < 12; t++) {
    // tile t ready in ALL waves; tile t+1 stays in flight across barrier.
    if (t < 11) asm volatile("s_waitcnt vmcnt(6)" ::: "memory");
    else        asm volatile("s_waitcnt vmcnt(0)" ::: "memory");
    __builtin_amdgcn_s_barrier();
    __builtin_amdgcn_sched_barrier(0);

    const bf16* Ab = smem + (t % 3) * TBUF;
    const bf16* Bb = Ab + ABUF;
#pragma unroll
    for (int ks = 0; ks < 2; ks++) {
      int cg = (ks * 4 + quad) ^ swz;
      bf16x8 a[4], b[4];
#pragma unroll
      for (int i = 0; i < 4; i++) a[i] = *(const bf16x8*)&Ab[(wm * 64 + i * 16 + l16) * 64 + cg * 8];
#pragma unroll
      for (int i = 0; i < 4; i++) b[i] = *(const bf16x8*)&Bb[(wn * 64 + i * 16 + l16) * 64 + cg * 8];
      // prefetch-issue half of tile t+2 (loads fly across the next barriers)
      if (t < 10) {
        if (ks == 0) stageH0((t + 2) * 64, smem + ((t + 2) % 3) * TBUF);
        else         stageH1((t + 2) * 64, smem + ((t + 2) % 3) * TBUF);
      }
      __builtin_amdgcn_s_barrier();             // pacing barrier (phase-lock)
      __builtin_amdgcn_sched_barrier(0);
      asm volatile("s_waitcnt lgkmcnt(0)" ::: "memory");
      __builtin_amdgcn_sched_barrier(0);
      __builtin_amdgcn_s_setprio(1);
      if (EPI == 2) {
#pragma unroll
        for (int mi = 0; mi < 4; mi++)
#pragma unroll
          for (int ni = 0; ni < 4; ni++)
            acc[mi][ni] = __builtin_amdgcn_mfma_f32_16x16x32_bf16(a[mi], b[ni], acc[mi][ni], 0, 0, 0);
      } else {
#pragma unroll
        for (int mi = 0; mi < 4; mi++)
#pragma unroll
          for (int ni = 0; ni < 4; ni++)
            acc[mi][ni] = __builtin_amdgcn_mfma_f32_16x16x32_bf16(b[ni], a[mi], acc[mi][ni], 0, 0, 0);
      }
      __builtin_amdgcn_s_setprio(0);
    }
  }

  if (EPI == 2) {
#pragma unroll
    for (int ni = 0; ni < 4; ni++) {
      int gc = bnl * 128 + wn * 64 + ni * 16 + l16;
      float bz = bias[gc];
      int h = gc >> 6, dd2 = gc & 63;
#pragma unroll
      for (int mi = 0; mi < 4; mi++) {
        int gm0 = bm * 256 + wm * 64 + mi * 16 + quad * 4;
        int b_ = gm0 >> 10, n0 = gm0 & 1023;
        bf16x4 pk;
#pragma unroll
        for (int r = 0; r < 4; r++) pk[r] = (bf16)(acc[mi][ni][r] + bz);
        *(bf16x4*)&Cb[(((size_t)b_ * NH + h) * HDIM + dd2) * NN + n0] = pk;
      }
    }
  } else if (EPI == 5) {
    // rope fused: acc cols gc..gc+3 = input qk-dims (two rope pairs).
    // cos/sin from TRANSPOSED table: tabs[j*1024 + n] -> lanes (n = l16-
    // consecutive) coalesce each 4B load into one line per 16 lanes.
    // QKr written direct (sectors merge across quads); QKrT staged in LDS.
    const int SP = 264;                  // pad: quad-rows land 8 banks apart
    bf16* stage = smem;                  // 128*264*2 = 67.6 KB, buffers 0/1 idle
    const float* cTb = tabs;
    const float* sTb = tabs + 65536;
#pragma unroll
    for (int mi = 0; mi < 4; mi++) {
      int gm = bm * 256 + wm * 64 + mi * 16 + l16;
      int n = gm & 1023, n_local = gm & 255;
#pragma unroll
      for (int ni = 0; ni < 4; ni++) {
        int gc = bnl * 128 + wn * 64 + ni * 16 + quad * 4;
        float4 bz = *(const float4*)&bias[gc];
        float v0 = acc[mi][ni][0] + bz.x;
        float v1 = acc[mi][ni][1] + bz.y;
        float v2 = acc[mi][ni][2] + bz.z;
        float v3 = acc[mi][ni][3] + bz.w;
        int h = gc >> 6, j2 = gc & 63;       // j2 % 4 == 0
        float c0 = cTb[(j2 + 0) * 1024 + n];
        float c1 = cTb[(j2 + 1) * 1024 + n];
        float c2 = cTb[(j2 + 2) * 1024 + n];
        float c3 = cTb[(j2 + 3) * 1024 + n];
        float s0 = sTb[(j2 + 0) * 1024 + n];
        float s1 = sTb[(j2 + 1) * 1024 + n];
        float s2 = sTb[(j2 + 2) * 1024 + n];
        float s3 = sTb[(j2 + 3) * 1024 + n];
        bf16 o1a = (bf16)(v0 * c0 - v1 * s0);
        bf16 o1b = (bf16)(v2 * c2 - v3 * s2);
        bf16 o2a = (bf16)(v0 * s1 + v1 * c1);
        bf16 o2b = (bf16)(v2 * s3 + v3 * c3);
        int p0 = j2 >> 1;                     // even
        bf16* qr = Cb + (size_t)gm * DD + h * 64;
        bf16x2 e0; e0[0] = o1a; e0[1] = o1b;
        bf16x2 e1; e1[0] = o2a; e1[1] = o2b;
        *(bf16x2*)&qr[p0] = e0;
        *(bf16x2*)&qr[32 + p0] = e1;
        int dl = wn * 64 + p0;                // stage row (head-local)
        stage[(size_t)dl * SP + n_local] = o1a;
        stage[(size_t)(dl + 1) * SP + n_local] = o1b;
        stage[(size_t)(dl + 32) * SP + n_local] = o2a;
        stage[(size_t)(dl + 33) * SP + n_local] = o2b;
      }
    }
    __syncthreads();
    // write-out: 128 rows x 256 n, 4 threads per row, 128B each
    {
      int row = tid >> 2, part = tid & 3;
      int hh = row >> 6, p = row & 63;
      int b_ = bm >> 2;
      int h = bnl * 2 + hh;
      bf16* dst = CT + ((size_t)(b_ * NH + h) * HDIM + p) * NN + (bm & 3) * 256 + part * 64;
      const bf16* srcr = &stage[(size_t)row * SP + part * 64];
#pragma unroll
      for (int j = 0; j < 8; j++)
        *(bf16x8*)&dst[j * 8] = *(const bf16x8*)&srcr[j * 8];
    }
  } else {
#pragma unroll
    for (int mi = 0; mi < 4; mi++) {
      int gm = bm * 256 + wm * 64 + mi * 16 + l16;
#pragma unroll
      for (int ni = 0; ni < 4; ni++) {
        int gc = bnl * 128 + wn * 64 + ni * 16 + quad * 4;
        float4 bz = *(const float4*)&bias[gc];
        float v0 = acc[mi][ni][0] + bz.x;
        float v1 = acc[mi][ni][1] + bz.y;
        float v2 = acc[mi][ni][2] + bz.z;
        float v3 = acc[mi][ni][3] + bz.w;
        size_t idx = (size_t)gm * DD + gc;
        if (EPI == 4) {
          bf16x4 g = *(const bf16x4*)&Gate[idx];
          float4 xr = *(const float4*)&Xres[idx];
          float4 o;
          o.x = xr.x + (float)g[0] * v0;
          o.y = xr.y + (float)g[1] * v1;
          o.z = xr.z + (float)g[2] * v2;
          o.w = xr.w + (float)g[3] * v3;
          *(float4*)&Cf[idx] = o;
        } else {
          bf16x4 pk;
          if (EPI == 0) {
            pk[0] = (bf16)fmaxf(v0, 0.f); pk[1] = (bf16)fmaxf(v1, 0.f);
            pk[2] = (bf16)fmaxf(v2, 0.f); pk[3] = (bf16)fmaxf(v3, 0.f);
          } else if (EPI == 1) {
            pk[0] = (bf16)v0; pk[1] = (bf16)v1; pk[2] = (bf16)v2; pk[3] = (bf16)v3;
          } else {
            pk[0] = (bf16)(1.f / (1.f + __expf(-v0)));
            pk[1] = (bf16)(1.f / (1.f + __expf(-v1)));
            pk[2] = (bf16)(1.f / (1.f + __expf(-v2)));
            pk[3] = (bf16)(1.f / (1.f + __expf(-v3)));
          }
          *(bf16x4*)&Cb[idx] = pk;
        }
      }
    }
  }
}

template<int EPI_LO, int EPI_HI, int NBN>
__global__ __launch_bounds__(512, 2) void gemm_kernel(
    const bf16* __restrict__ Aop, const bf16* __restrict__ W,
    const float* __restrict__ bias_lo, const float* __restrict__ bias_hi,
    bf16* __restrict__ C_lo, bf16* __restrict__ C_hi, bf16* __restrict__ CT,
    float* __restrict__ Cf,
    const float* __restrict__ Xres, const bf16* __restrict__ Gate,
    const float* __restrict__ tabs) {
  __shared__ __attribute__((aligned(16))) bf16 smem[3 * TBUF];  // 144 KB
  int blk = blockIdx.x;
  int xcd = blk & 7, slot = blk >> 3;
  int bm = xcd * 8 + slot / NBN;
  int bn = slot % NBN;
  if (NBN == 12 && bn >= 6) {
    gemm_body<EPI_HI>(bm, bn, bn - 6, Aop, W, bias_hi, C_hi, CT, Cf, Xres, Gate, tabs, smem);
  } else {
    gemm_body<EPI_LO>(bm, bn, bn, Aop, W, bias_lo, C_lo, CT, Cf, Xres, Gate, tabs, smem);
  }
}

// ============================================================================
// Final GEMM (out-proj + gate + residual): 256x128 tile, 4 waves 128x64,
// 2-barrier loop, 48KB LDS — epilogue is HBM-heavy, needs multi-block TLP.
// ============================================================================
template<int EPI>
__device__ __forceinline__ void gemm0_body(
    int bm, int bn, int bnl,
    const bf16* __restrict__ Aop, const bf16* __restrict__ W,
    const float* __restrict__ bias,
    bf16* __restrict__ Cb, float* __restrict__ Cf,
    const float* __restrict__ Xres, const bf16* __restrict__ Gate,
    bf16* As, bf16* Bs) {
  int tid = threadIdx.x;
  int wave = tid >> 6, lane = tid & 63;
  int quad = lane >> 4, l16 = lane & 15;
  int wm = wave & 1, wn = wave >> 1;
  int sr = lane >> 3;
  int smcg = (lane & 7) ^ sr;

  const bf16* Ag = Aop + (size_t)(bm * 256) * DD;
  const bf16* Bg = W + (size_t)(bn * 128) * DD;

  floatx4 acc[8][4];
#pragma unroll
  for (int i = 0; i < 8; i++)
#pragma unroll
    for (int j = 0; j < 4; j++)
      acc[i][j] = (floatx4){0.f, 0.f, 0.f, 0.f};

  int swzA = (l16 & 7);

  for (int k0 = 0; k0 < DD; k0 += 64) {
    __syncthreads();
#pragma unroll
    for (int it = 0; it < 8; it++) {
      int c = it * 4 + wave;
      int row = c * 8 + sr;
      async_cp16(Ag + (size_t)row * DD + k0 + smcg * 8, &As[c * 512]);
    }
#pragma unroll
    for (int it = 0; it < 4; it++) {
      int c = it * 4 + wave;
      int row = c * 8 + sr;
      async_cp16(Bg + (size_t)row * DD + k0 + smcg * 8, &Bs[c * 512]);
    }
    __syncthreads();
#pragma unroll
    for (int ks = 0; ks < 2; ks++) {
      int cg = (ks * 4 + quad) ^ swzA;
      bf16x8 a[8], b[4];
#pragma unroll
      for (int i = 0; i < 8; i++) a[i] = *(const bf16x8*)&As[(wm * 128 + i * 16 + l16) * 64 + cg * 8];
#pragma unroll
      for (int i = 0; i < 4; i++) b[i] = *(const bf16x8*)&Bs[(wn * 64 + i * 16 + l16) * 64 + cg * 8];
#pragma unroll
      for (int mi = 0; mi < 8; mi++)
#pragma unroll
        for (int ni = 0; ni < 4; ni++)
          acc[mi][ni] = __builtin_amdgcn_mfma_f32_16x16x32_bf16(b[ni], a[mi], acc[mi][ni], 0, 0, 0);
    }
  }

#pragma unroll
  for (int mi = 0; mi < 8; mi++) {
    int gm = bm * 256 + wm * 128 + mi * 16 + l16;
#pragma unroll
    for (int ni = 0; ni < 4; ni++) {
      int gc = bnl * 128 + wn * 64 + ni * 16 + quad * 4;
      float4 bz = *(const float4*)&bias[gc];
      float v0 = acc[mi][ni][0] + bz.x;
      float v1 = acc[mi][ni][1] + bz.y;
      float v2 = acc[mi][ni][2] + bz.z;
      float v3 = acc[mi][ni][3] + bz.w;
      size_t idx = (size_t)gm * DD + gc;
      if (EPI == 4) {
        bf16x4 g = *(const bf16x4*)&Gate[idx];
        float4 xr = *(const float4*)&Xres[idx];
        float4 o;
        o.x = xr.x + (float)g[0] * v0;
        o.y = xr.y + (float)g[1] * v1;
        o.z = xr.z + (float)g[2] * v2;
        o.w = xr.w + (float)g[3] * v3;
        *(float4*)&Cf[idx] = o;
      } else {
        bf16x4 pk;
        pk[0] = (bf16)v0; pk[1] = (bf16)v1; pk[2] = (bf16)v2; pk[3] = (bf16)v3;
        *(bf16x4*)&Cb[idx] = pk;
      }
    }
  }
}

template<int EPI, int NBN>
__global__ __launch_bounds__(256, 2) void gemm0_kernel(
    const bf16* __restrict__ Aop, const bf16* __restrict__ W,
    const float* __restrict__ bias,
    bf16* __restrict__ Cb, float* __restrict__ Cf,
    const float* __restrict__ Xres, const bf16* __restrict__ Gate) {
  __shared__ bf16 As[256 * 64];
  __shared__ bf16 Bs[128 * 64];
  int blk = blockIdx.x;
  int xcd = blk & 7, slot = blk >> 3;
  int bm = xcd * 8 + slot / NBN;
  int bn = slot % NBN;
  gemm0_body<EPI>(bm, bn, bn, Aop, W, bias, Cb, Cf, Xres, Gate, As, Bs);
}

// ---- Attention (single-pass): T = QKr^T @ V (64x64, once per bh), then
//      attn = QKr @ T / 8 for all 1024 rows. Grid = B*H = 192 blocks.
//      Phase 2 uses swapped MFMA operands -> packed bf16x4 column stores.
__global__ __launch_bounds__(256) void attn_kernel(const bf16* __restrict__ QKr,
    const bf16* __restrict__ QKrT, const bf16* __restrict__ VT, bf16* __restrict__ attn) {
  __shared__ float Tp[64][64];
  __shared__ bf16 Tbf[64][72];
  int blk = blockIdx.x;
  int xcd = blk & 7, bhl = blk >> 3;
  int bh = xcd * 24 + bhl;
  int tid = threadIdx.x, wave = tid >> 6, lane = tid & 63;
  int quad = lane >> 4, l16 = lane & 15;
  const bf16* Qt = QKrT + (size_t)bh * (HDIM * NN);
  const bf16* Vt = VT + (size_t)bh * (HDIM * NN);

  floatx4 acc[4][4];
#pragma unroll
  for (int i = 0; i < 4; i++)
#pragma unroll
    for (int j = 0; j < 4; j++)
      acc[i][j] = (floatx4){0.f, 0.f, 0.f, 0.f};

  int kbase = wave * 256;
#pragma unroll
  for (int k0 = 0; k0 < 256; k0 += 32) {
    bf16x8 a[4], b[4];
#pragma unroll
    for (int i = 0; i < 4; i++) a[i] = *(const bf16x8*)&Qt[(size_t)(i * 16 + l16) * NN + kbase + k0 + quad * 8];
#pragma unroll
    for (int i = 0; i < 4; i++) b[i] = *(const bf16x8*)&Vt[(size_t)(i * 16 + l16) * NN + kbase + k0 + quad * 8];
#pragma unroll
    for (int mi = 0; mi < 4; mi++)
#pragma unroll
      for (int ni = 0; ni < 4; ni++)
        acc[mi][ni] = __builtin_amdgcn_mfma_f32_16x16x32_bf16(a[mi], b[ni], acc[mi][ni], 0, 0, 0);
  }
#pragma unroll
  for (int w = 0; w < 4; w++) {
    if (wave == w) {
#pragma unroll
      for (int mi = 0; mi < 4; mi++)
#pragma unroll
        for (int ni = 0; ni < 4; ni++)
#pragma unroll
          for (int r = 0; r < 4; r++) {
            float val = acc[mi][ni][r];
            float* p = &Tp[mi * 16 + quad * 4 + r][ni * 16 + l16];
            if (w == 0) *p = val; else *p += val;
          }
    }
    __syncthreads();
  }
  for (int e = tid; e < 4096; e += 256) {
    int d1 = e >> 6, d2 = e & 63;
    Tbf[d2][d1] = (bf16)(Tp[d1][d2] * 0.125f);
  }
  __syncthreads();

  int b_ = bh / NH, h_ = bh % NH;
  const bf16* Q = QKr + (size_t)(b_ * NN) * DD + h_ * HDIM;
  bf16* Ao = attn + (size_t)(b_ * NN) * DD + h_ * HDIM;
  bf16x8 Bf[4][2];
#pragma unroll
  for (int ni = 0; ni < 4; ni++)
#pragma unroll
    for (int ks = 0; ks < 2; ks++)
      Bf[ni][ks] = *(const bf16x8*)&Tbf[ni * 16 + l16][ks * 32 + quad * 8];

#pragma unroll
  for (int mi = 0; mi < 16; mi++) {
    int nrow = wave * 256 + mi * 16;
    bf16x8 a0 = *(const bf16x8*)&Q[(size_t)(nrow + l16) * DD + quad * 8];
    bf16x8 a1 = *(const bf16x8*)&Q[(size_t)(nrow + l16) * DD + 32 + quad * 8];
    floatx4 o[4];
#pragma unroll
    for (int ni = 0; ni < 4; ni++) o[ni] = (floatx4){0.f, 0.f, 0.f, 0.f};
#pragma unroll
    for (int ni = 0; ni < 4; ni++) {
      o[ni] = __builtin_amdgcn_mfma_f32_16x16x32_bf16(Bf[ni][0], a0, o[ni], 0, 0, 0);
      o[ni] = __builtin_amdgcn_mfma_f32_16x16x32_bf16(Bf[ni][1], a1, o[ni], 0, 0, 0);
    }
#pragma unroll
    for (int ni = 0; ni < 4; ni++) {
      bf16x4 pk;
#pragma unroll
      for (int r = 0; r < 4; r++) pk[r] = (bf16)o[ni][r];
      *(bf16x4*)&Ao[(size_t)(nrow + l16) * DD + ni * 16 + quad * 4] = pk;
    }
  }
}

extern "C" void kernel_launch(void* const* d_in, const int* in_sizes, int n_in,
                              void* d_out, int out_size, void* d_ws, size_t ws_size,
                              hipStream_t stream) {
  const float* x      = (const float*)d_in[0];
  const float* rope   = (const float*)d_in[1];
  const float* ln_w   = (const float*)d_in[2];
  const float* ln_b   = (const float*)d_in[3];
  const float* enc_w  = (const float*)d_in[4];
  const float* enc_b  = (const float*)d_in[5];
  const float* qk_w   = (const float*)d_in[6];
  const float* qk_b   = (const float*)d_in[7];
  const float* v_w    = (const float*)d_in[8];
  const float* v_b    = (const float*)d_in[9];
  const float* out_w  = (const float*)d_in[10];
  const float* out_b  = (const float*)d_in[11];
  const float* gate_w = (const float*)d_in[12];
  const float* gate_b = (const float*)d_in[13];

  char* w = (char*)d_ws;
  const size_t S = (size_t)MTOT * DD * 2;
  bf16* s0 = (bf16*)(w);
  bf16* s1 = (bf16*)(w + S);
  bf16* s2 = (bf16*)(w + 2 * S);
  bf16* s3 = (bf16*)(w + 3 * S);
  bf16* s4 = (bf16*)(w + 4 * S);
  bf16* s5 = (bf16*)(w + 5 * S);
  bf16* Wb = (bf16*)(w + 6 * S);
  float* tabs = (float*)(w + 6 * S + 6 * 1024 * 1024);  // past Wb (5.9 MB)

  bf16* A = s0;
  bf16* L = s1;
  bf16* Gate = s2;
  bf16* QKr = s3;
  bf16* QKrT = s4;
  bf16* VT = s5;
  bf16* attnb = s1;

  prep_kernel<<<dim3(7232), dim3(256), 0, stream>>>(
      x, ln_w, ln_b, A, enc_w, gate_w, qk_w, v_w, out_w, Wb, rope, tabs);

  gemm_kernel<0, 3, 12><<<dim3(768), dim3(512), 0, stream>>>(
      A, Wb, enc_b, gate_b, L, Gate, nullptr, nullptr, nullptr, nullptr, nullptr);
  gemm_kernel<5, 2, 12><<<dim3(768), dim3(512), 0, stream>>>(
      L, Wb + 2 * (size_t)WELEM, qk_b, v_b, QKr, VT, QKrT, nullptr, nullptr, nullptr, tabs);
  attn_kernel<<<dim3(BB * NH), dim3(256), 0, stream>>>(QKr, QKrT, VT, attnb);
  gemm0_kernel<4, 6><<<dim3(384), dim3(256), 0, stream>>>(
      attnb, Wb + 4 * (size_t)WELEM, out_b, nullptr, (float*)d_out, x, Gate);
}

// Round 7
// 321.673 us; speedup vs baseline: 1.0405x; 1.0405x over previous
//
#include <hip/hip_runtime.h>

typedef __bf16 bf16;
typedef __bf16 bf16x2 __attribute__((ext_vector_type(2)));
typedef __bf16 bf16x4 __attribute__((ext_vector_type(4)));
typedef __bf16 bf16x8 __attribute__((ext_vector_type(8)));
typedef float floatx4 __attribute__((ext_vector_type(4)));

#define DD 768
#define NH 12
#define HDIM 64
#define BB 16
#define NN 1024
#define MTOT (BB*NN)   // 16384
#define WELEM (DD*DD)  // 589824

// Pipelined-GEMM LDS geometry: one K-tile buffer = A(256x64) + B(128x64) bf16
#define ABUF 16384
#define BBUF 8192
#define TBUF (ABUF + BBUF)   // 24576 bf16 = 48KB; 3 buffers = 144KB

__device__ __forceinline__ void async_cp16(const void* g, void* l) {
  __builtin_amdgcn_global_load_lds((const __attribute__((address_space(1))) void*)g,
                                   (__attribute__((address_space(3))) void*)l, 16, 0, 0);
}

// ---- prep: LN (blocks 0..4095), weight conv (4096..6975), sincos (6976..7231)
// sincos table built TRANSPOSED: tabs[j*1024 + n] = cos(rope[n][j]), second
// 64K-f32 half = sin.
__global__ __launch_bounds__(256) void prep_kernel(
    const float* __restrict__ x, const float* __restrict__ lnw,
    const float* __restrict__ lnb, bf16* __restrict__ A,
    const float* __restrict__ w0, const float* __restrict__ w1,
    const float* __restrict__ w2, const float* __restrict__ w3,
    const float* __restrict__ w4, bf16* __restrict__ Wb,
    const float* __restrict__ rope, float* __restrict__ tabs) {
  int blk = blockIdx.x;
  int tid = threadIdx.x;
  if (blk < 4096) {
    // ---------------- LayerNorm: x (f32) -> A (bf16) ----------------
    int row = blk * 4 + (tid >> 6);
    int lane = tid & 63;
    const float4* xr = (const float4*)(x + (size_t)row * DD);
    float4 v[3];
    float s = 0.f;
#pragma unroll
    for (int i = 0; i < 3; i++) {
      v[i] = xr[lane + 64 * i];
      s += v[i].x + v[i].y + v[i].z + v[i].w;
    }
#pragma unroll
    for (int o = 32; o; o >>= 1) s += __shfl_xor(s, o);
    float mu = s * (1.f / 768.f);
    float vs = 0.f;
#pragma unroll
    for (int i = 0; i < 3; i++) {
      float dx;
      dx = v[i].x - mu; vs += dx * dx;
      dx = v[i].y - mu; vs += dx * dx;
      dx = v[i].z - mu; vs += dx * dx;
      dx = v[i].w - mu; vs += dx * dx;
    }
#pragma unroll
    for (int o = 32; o; o >>= 1) vs += __shfl_xor(vs, o);
    float rstd = rsqrtf(vs * (1.f / 768.f) + 1e-5f);
    const float4* wv = (const float4*)lnw;
    const float4* bv = (const float4*)lnb;
    bf16* Ar = A + (size_t)row * DD;
#pragma unroll
    for (int i = 0; i < 3; i++) {
      int c4 = lane + 64 * i;
      float4 ww = wv[c4], bb = bv[c4];
      bf16x4 pk;
      pk[0] = (bf16)((v[i].x - mu) * rstd * ww.x + bb.x);
      pk[1] = (bf16)((v[i].y - mu) * rstd * ww.y + bb.y);
      pk[2] = (bf16)((v[i].z - mu) * rstd * ww.z + bb.z);
      pk[3] = (bf16)((v[i].w - mu) * rstd * ww.w + bb.w);
      *(bf16x4*)(Ar + c4 * 4) = pk;
    }
  } else if (blk < 4096 + 2880) {
    // ------- Weights f32 -> bf16, order: enc, gate, qk, v, out -------
    int i = (blk - 4096) * 256 + tid;
    int which = i / (WELEM / 4);
    int off = (i % (WELEM / 4)) * 4;
    const float* s = which == 0 ? w0 : which == 1 ? w1 : which == 2 ? w2 : which == 3 ? w3 : w4;
    float4 v = *(const float4*)(s + off);
    bf16x4 pk;
    pk[0] = (bf16)v.x; pk[1] = (bf16)v.y; pk[2] = (bf16)v.z; pk[3] = (bf16)v.w;
    *(bf16x4*)(Wb + (size_t)i * 4) = pk;
  } else {
    // ---- sincos table TRANSPOSED: i = j*1024 + n; angle = rope[n*64+j] ----
    int i = (blk - 6976) * 256 + tid;
    int j = i >> 10, n = i & 1023;
    float a = rope[n * 64 + j];
    float s, c;
    __sincosf(a, &s, &c);
    tabs[i] = c;
    tabs[65536 + i] = s;
  }
}

// ============================================================================
// Pipelined GEMM: 256x128 block tile, 8 waves, 64x64/wave, BK=64,
// triple-buffered LDS, prefetch distance 2, counted vmcnt(6).
// EPI: 0 relu->bf16, 1 plain->bf16, 2 transposed (B,H,HD,N)->bf16,
//      3 sigmoid->bf16, 4 final f32, 5 rope-fused dual write (QKr + QKrT).
// EPI 0/1/3/5: bf16 outputs staged through LDS -> full-sector 128B global
// stores (kills L2 read-modify-write FETCH amplification).
// EPI != 2: MFMA operands swapped (computes C^T) -> packed row-major stores.
// ============================================================================
template<int EPI>
__device__ __forceinline__ void gemm_body(
    int bm, int bn, int bnl,
    const bf16* __restrict__ Aop, const bf16* __restrict__ W,
    const float* __restrict__ bias,
    bf16* __restrict__ Cb, bf16* __restrict__ CT, float* __restrict__ Cf,
    const float* __restrict__ Xres, const bf16* __restrict__ Gate,
    const float* __restrict__ tabs, bf16* smem) {
  int tid = threadIdx.x;
  int w = tid >> 6, lane = tid & 63;
  int quad = lane >> 4, l16 = lane & 15;
  int wm = w >> 1, wn = w & 1;          // 4M x 2N wave grid -> 64x64 per wave
  int sr = lane >> 3;                   // row within 8-row chunk
  int scg = (lane & 7) ^ sr;            // pre-swizzled source colgroup
  int swz = l16 & 7;

  const bf16* Ag = Aop + (size_t)(bm * 256) * DD;
  const bf16* Bg = W + (size_t)(bn * 128) * DD;
  const bf16* srcA = Ag + (size_t)(w * 8 + sr) * DD + scg * 8;
  const bf16* srcB = Bg + (size_t)(w * 8 + sr) * DD + scg * 8;

  floatx4 acc[4][4];
#pragma unroll
  for (int i = 0; i < 4; i++)
#pragma unroll
    for (int j = 0; j < 4; j++)
      acc[i][j] = (floatx4){0.f, 0.f, 0.f, 0.f};

  // 6 global_load_lds per wave per K-tile, split in two 3-load halves
  auto stageH0 = [&](int k0, bf16* buf) {
    async_cp16(srcA + (size_t)0 * (64 * DD) + k0, buf + (w + 0) * 512);
    async_cp16(srcA + (size_t)1 * (64 * DD) + k0, buf + (w + 8) * 512);
    async_cp16(srcB + k0, buf + ABUF + w * 512);
  };
  auto stageH1 = [&](int k0, bf16* buf) {
    async_cp16(srcA + (size_t)2 * (64 * DD) + k0, buf + (w + 16) * 512);
    async_cp16(srcA + (size_t)3 * (64 * DD) + k0, buf + (w + 24) * 512);
    async_cp16(srcB + (size_t)64 * DD + k0, buf + ABUF + (w + 8) * 512);
  };

  // prologue: tiles 0 and 1 in flight (12 outstanding vmcnt events/wave)
  stageH0(0, smem);               stageH1(0, smem);
  stageH0(64, smem + TBUF);       stageH1(64, smem + TBUF);

#pragma unroll
  for (int t = 0; t < 12; t++) {
    // tile t ready in ALL waves; tile t+1 stays in flight across barrier.
    if (t < 11) asm volatile("s_waitcnt vmcnt(6)" ::: "memory");
    else        asm volatile("s_waitcnt vmcnt(0)" ::: "memory");
    __builtin_amdgcn_s_barrier();
    __builtin_amdgcn_sched_barrier(0);

    const bf16* Ab = smem + (t % 3) * TBUF;
    const bf16* Bb = Ab + ABUF;
#pragma unroll
    for (int ks = 0; ks < 2; ks++) {
      int cg = (ks * 4 + quad) ^ swz;
      bf16x8 a[4], b[4];
#pragma unroll
      for (int i = 0; i < 4; i++) a[i] = *(const bf16x8*)&Ab[(wm * 64 + i * 16 + l16) * 64 + cg * 8];
#pragma unroll
      for (int i = 0; i < 4; i++) b[i] = *(const bf16x8*)&Bb[(wn * 64 + i * 16 + l16) * 64 + cg * 8];
      // prefetch-issue half of tile t+2 (loads fly across the next barriers)
      if (t < 10) {
        if (ks == 0) stageH0((t + 2) * 64, smem + ((t + 2) % 3) * TBUF);
        else         stageH1((t + 2) * 64, smem + ((t + 2) % 3) * TBUF);
      }
      __builtin_amdgcn_s_barrier();             // pacing barrier (phase-lock)
      __builtin_amdgcn_sched_barrier(0);
      asm volatile("s_waitcnt lgkmcnt(0)" ::: "memory");
      __builtin_amdgcn_sched_barrier(0);
      __builtin_amdgcn_s_setprio(1);
      if (EPI == 2) {
#pragma unroll
        for (int mi = 0; mi < 4; mi++)
#pragma unroll
          for (int ni = 0; ni < 4; ni++)
            acc[mi][ni] = __builtin_amdgcn_mfma_f32_16x16x32_bf16(a[mi], b[ni], acc[mi][ni], 0, 0, 0);
      } else {
#pragma unroll
        for (int mi = 0; mi < 4; mi++)
#pragma unroll
          for (int ni = 0; ni < 4; ni++)
            acc[mi][ni] = __builtin_amdgcn_mfma_f32_16x16x32_bf16(b[ni], a[mi], acc[mi][ni], 0, 0, 0);
      }
      __builtin_amdgcn_s_setprio(0);
    }
  }

  if (EPI == 2) {
#pragma unroll
    for (int ni = 0; ni < 4; ni++) {
      int gc = bnl * 128 + wn * 64 + ni * 16 + l16;
      float bz = bias[gc];
      int h = gc >> 6, dd2 = gc & 63;
#pragma unroll
      for (int mi = 0; mi < 4; mi++) {
        int gm0 = bm * 256 + wm * 64 + mi * 16 + quad * 4;
        int b_ = gm0 >> 10, n0 = gm0 & 1023;
        bf16x4 pk;
#pragma unroll
        for (int r = 0; r < 4; r++) pk[r] = (bf16)(acc[mi][ni][r] + bz);
        *(bf16x4*)&Cb[(((size_t)b_ * NH + h) * HDIM + dd2) * NN + n0] = pk;
      }
    }
  } else if (EPI == 5) {
    // rope fused. Single LDS stage, n-major: st2[head][n(256)][72] bf16
    // (72 = 64 dims + pad, 144B rows = 16B-aligned). Then two coalesced
    // write-outs: QKr (row read -> 128B store), QKrT (column gather -> 128B).
    const int ST2H = 256 * 72;           // per-head region, elems
    bf16* st2 = smem;                    // 2*256*72*2 = 73728 B; K-loop done
    const float* cTb = tabs;
    const float* sTb = tabs + 65536;
    __syncthreads();                     // all waves' K-loop LDS reads done
#pragma unroll
    for (int mi = 0; mi < 4; mi++) {
      int gm = bm * 256 + wm * 64 + mi * 16 + l16;
      int n = gm & 1023, n_local = gm & 255;
#pragma unroll
      for (int ni = 0; ni < 4; ni++) {
        int gc = bnl * 128 + wn * 64 + ni * 16 + quad * 4;
        float4 bz = *(const float4*)&bias[gc];
        float v0 = acc[mi][ni][0] + bz.x;
        float v1 = acc[mi][ni][1] + bz.y;
        float v2 = acc[mi][ni][2] + bz.z;
        float v3 = acc[mi][ni][3] + bz.w;
        int j2 = gc & 63;                 // j2 % 4 == 0
        float c0 = cTb[(j2 + 0) * 1024 + n];
        float c1 = cTb[(j2 + 1) * 1024 + n];
        float c2 = cTb[(j2 + 2) * 1024 + n];
        float c3 = cTb[(j2 + 3) * 1024 + n];
        float s0 = sTb[(j2 + 0) * 1024 + n];
        float s1 = sTb[(j2 + 1) * 1024 + n];
        float s2 = sTb[(j2 + 2) * 1024 + n];
        float s3 = sTb[(j2 + 3) * 1024 + n];
        bf16x2 e0, e1;
        e0[0] = (bf16)(v0 * c0 - v1 * s0);        // dim p0
        e0[1] = (bf16)(v2 * c2 - v3 * s2);        // dim p0+1
        e1[0] = (bf16)(v0 * s1 + v1 * c1);        // dim 32+p0
        e1[1] = (bf16)(v2 * s3 + v3 * c3);        // dim 33+p0
        int p0 = j2 >> 1;                          // even
        bf16* rowp = st2 + wn * ST2H + n_local * 72;
        *(bf16x2*)&rowp[p0] = e0;
        *(bf16x2*)&rowp[32 + p0] = e1;
      }
    }
    __syncthreads();
    // write-out 1: QKr — thread (n_local, hh) reads contiguous 64-dim row
    {
      int n_local = tid >> 1, hh = tid & 1;
      int gm = bm * 256 + n_local;
      int h = bnl * 2 + hh;
      bf16* dst = Cb + (size_t)gm * DD + h * 64;
      const bf16* srcr = st2 + hh * ST2H + n_local * 72;
#pragma unroll
      for (int j = 0; j < 8; j++)
        *(bf16x8*)&dst[j * 8] = *(const bf16x8*)&srcr[j * 8];
    }
    // write-out 2: QKrT — thread (dim row, part) gathers 64-n column
    {
      int row = tid >> 2, part = tid & 3;
      int hh = row >> 6, p = row & 63;
      int b_ = bm >> 2;
      int h = bnl * 2 + hh;
      __attribute__((aligned(16))) bf16 buf[64];
#pragma unroll
      for (int k = 0; k < 64; k++)
        buf[k] = st2[hh * ST2H + (part * 64 + k) * 72 + p];
      bf16* dst = CT + ((size_t)(b_ * NH + h) * HDIM + p) * NN + (bm & 3) * 256 + part * 64;
#pragma unroll
      for (int j = 0; j < 8; j++)
        *(bf16x8*)&dst[j * 8] = *(const bf16x8*)&buf[j * 8];
    }
  } else if (EPI == 4) {
#pragma unroll
    for (int mi = 0; mi < 4; mi++) {
      int gm = bm * 256 + wm * 64 + mi * 16 + l16;
#pragma unroll
      for (int ni = 0; ni < 4; ni++) {
        int gc = bnl * 128 + wn * 64 + ni * 16 + quad * 4;
        float4 bz = *(const float4*)&bias[gc];
        float v0 = acc[mi][ni][0] + bz.x;
        float v1 = acc[mi][ni][1] + bz.y;
        float v2 = acc[mi][ni][2] + bz.z;
        float v3 = acc[mi][ni][3] + bz.w;
        size_t idx = (size_t)gm * DD + gc;
        bf16x4 g = *(const bf16x4*)&Gate[idx];
        float4 xr = *(const float4*)&Xres[idx];
        float4 o;
        o.x = xr.x + (float)g[0] * v0;
        o.y = xr.y + (float)g[1] * v1;
        o.z = xr.z + (float)g[2] * v2;
        o.w = xr.w + (float)g[3] * v3;
        *(float4*)&Cf[idx] = o;
      }
    }
  } else {
    // EPI 0/1/3: stage C tile [256][136] in LDS, coalesced 128B write-out.
    const int SPC = 136;                 // 272B rows, 16B-aligned
    bf16* st = smem;                     // 256*136*2 = 69632 B
    __syncthreads();                     // all waves' K-loop LDS reads done
#pragma unroll
    for (int mi = 0; mi < 4; mi++) {
      int rloc = wm * 64 + mi * 16 + l16;
#pragma unroll
      for (int ni = 0; ni < 4; ni++) {
        int cloc = wn * 64 + ni * 16 + quad * 4;
        int gc = bnl * 128 + cloc;
        float4 bz = *(const float4*)&bias[gc];
        float v0 = acc[mi][ni][0] + bz.x;
        float v1 = acc[mi][ni][1] + bz.y;
        float v2 = acc[mi][ni][2] + bz.z;
        float v3 = acc[mi][ni][3] + bz.w;
        bf16x4 pk;
        if (EPI == 0) {
          pk[0] = (bf16)fmaxf(v0, 0.f); pk[1] = (bf16)fmaxf(v1, 0.f);
          pk[2] = (bf16)fmaxf(v2, 0.f); pk[3] = (bf16)fmaxf(v3, 0.f);
        } else if (EPI == 1) {
          pk[0] = (bf16)v0; pk[1] = (bf16)v1; pk[2] = (bf16)v2; pk[3] = (bf16)v3;
        } else {
          pk[0] = (bf16)(1.f / (1.f + __expf(-v0)));
          pk[1] = (bf16)(1.f / (1.f + __expf(-v1)));
          pk[2] = (bf16)(1.f / (1.f + __expf(-v2)));
          pk[3] = (bf16)(1.f / (1.f + __expf(-v3)));
        }
        *(bf16x4*)&st[rloc * SPC + cloc] = pk;
      }
    }
    __syncthreads();
    {
      int row = tid >> 1, half = tid & 1;
      int gm = bm * 256 + row;
      bf16* dst = Cb + (size_t)gm * DD + bnl * 128 + half * 64;
      const bf16* sr = &st[row * SPC + half * 64];
#pragma unroll
      for (int j = 0; j < 8; j++)
        *(bf16x8*)&dst[j * 8] = *(const bf16x8*)&sr[j * 8];
    }
  }
}

template<int EPI_LO, int EPI_HI, int NBN>
__global__ __launch_bounds__(512, 2) void gemm_kernel(
    const bf16* __restrict__ Aop, const bf16* __restrict__ W,
    const float* __restrict__ bias_lo, const float* __restrict__ bias_hi,
    bf16* __restrict__ C_lo, bf16* __restrict__ C_hi, bf16* __restrict__ CT,
    float* __restrict__ Cf,
    const float* __restrict__ Xres, const bf16* __restrict__ Gate,
    const float* __restrict__ tabs) {
  __shared__ __attribute__((aligned(16))) bf16 smem[3 * TBUF];  // 144 KB
  int blk = blockIdx.x;
  int xcd = blk & 7, slot = blk >> 3;
  int bm = xcd * 8 + slot / NBN;
  int bn = slot % NBN;
  if (NBN == 12 && bn >= 6) {
    gemm_body<EPI_HI>(bm, bn, bn - 6, Aop, W, bias_hi, C_hi, CT, Cf, Xres, Gate, tabs, smem);
  } else {
    gemm_body<EPI_LO>(bm, bn, bn, Aop, W, bias_lo, C_lo, CT, Cf, Xres, Gate, tabs, smem);
  }
}

// ============================================================================
// Final GEMM (out-proj + gate + residual): 256x128 tile, 4 waves 128x64,
// 2-barrier loop, 48KB LDS — epilogue is HBM-heavy, needs multi-block TLP.
// ============================================================================
template<int EPI>
__device__ __forceinline__ void gemm0_body(
    int bm, int bn, int bnl,
    const bf16* __restrict__ Aop, const bf16* __restrict__ W,
    const float* __restrict__ bias,
    bf16* __restrict__ Cb, float* __restrict__ Cf,
    const float* __restrict__ Xres, const bf16* __restrict__ Gate,
    bf16* As, bf16* Bs) {
  int tid = threadIdx.x;
  int wave = tid >> 6, lane = tid & 63;
  int quad = lane >> 4, l16 = lane & 15;
  int wm = wave & 1, wn = wave >> 1;
  int sr = lane >> 3;
  int smcg = (lane & 7) ^ sr;

  const bf16* Ag = Aop + (size_t)(bm * 256) * DD;
  const bf16* Bg = W + (size_t)(bn * 128) * DD;

  floatx4 acc[8][4];
#pragma unroll
  for (int i = 0; i < 8; i++)
#pragma unroll
    for (int j = 0; j < 4; j++)
      acc[i][j] = (floatx4){0.f, 0.f, 0.f, 0.f};

  int swzA = (l16 & 7);

  for (int k0 = 0; k0 < DD; k0 += 64) {
    __syncthreads();
#pragma unroll
    for (int it = 0; it < 8; it++) {
      int c = it * 4 + wave;
      int row = c * 8 + sr;
      async_cp16(Ag + (size_t)row * DD + k0 + smcg * 8, &As[c * 512]);
    }
#pragma unroll
    for (int it = 0; it < 4; it++) {
      int c = it * 4 + wave;
      int row = c * 8 + sr;
      async_cp16(Bg + (size_t)row * DD + k0 + smcg * 8, &Bs[c * 512]);
    }
    __syncthreads();
#pragma unroll
    for (int ks = 0; ks < 2; ks++) {
      int cg = (ks * 4 + quad) ^ swzA;
      bf16x8 a[8], b[4];
#pragma unroll
      for (int i = 0; i < 8; i++) a[i] = *(const bf16x8*)&As[(wm * 128 + i * 16 + l16) * 64 + cg * 8];
#pragma unroll
      for (int i = 0; i < 4; i++) b[i] = *(const bf16x8*)&Bs[(wn * 64 + i * 16 + l16) * 64 + cg * 8];
#pragma unroll
      for (int mi = 0; mi < 8; mi++)
#pragma unroll
        for (int ni = 0; ni < 4; ni++)
          acc[mi][ni] = __builtin_amdgcn_mfma_f32_16x16x32_bf16(b[ni], a[mi], acc[mi][ni], 0, 0, 0);
    }
  }

#pragma unroll
  for (int mi = 0; mi < 8; mi++) {
    int gm = bm * 256 + wm * 128 + mi * 16 + l16;
#pragma unroll
    for (int ni = 0; ni < 4; ni++) {
      int gc = bnl * 128 + wn * 64 + ni * 16 + quad * 4;
      float4 bz = *(const float4*)&bias[gc];
      float v0 = acc[mi][ni][0] + bz.x;
      float v1 = acc[mi][ni][1] + bz.y;
      float v2 = acc[mi][ni][2] + bz.z;
      float v3 = acc[mi][ni][3] + bz.w;
      size_t idx = (size_t)gm * DD + gc;
      if (EPI == 4) {
        bf16x4 g = *(const bf16x4*)&Gate[idx];
        float4 xr = *(const float4*)&Xres[idx];
        float4 o;
        o.x = xr.x + (float)g[0] * v0;
        o.y = xr.y + (float)g[1] * v1;
        o.z = xr.z + (float)g[2] * v2;
        o.w = xr.w + (float)g[3] * v3;
        *(float4*)&Cf[idx] = o;
      } else {
        bf16x4 pk;
        pk[0] = (bf16)v0; pk[1] = (bf16)v1; pk[2] = (bf16)v2; pk[3] = (bf16)v3;
        *(bf16x4*)&Cb[idx] = pk;
      }
    }
  }
}

template<int EPI, int NBN>
__global__ __launch_bounds__(256, 2) void gemm0_kernel(
    const bf16* __restrict__ Aop, const bf16* __restrict__ W,
    const float* __restrict__ bias,
    bf16* __restrict__ Cb, float* __restrict__ Cf,
    const float* __restrict__ Xres, const bf16* __restrict__ Gate) {
  __shared__ bf16 As[256 * 64];
  __shared__ bf16 Bs[128 * 64];
  int blk = blockIdx.x;
  int xcd = blk & 7, slot = blk >> 3;
  int bm = xcd * 8 + slot / NBN;
  int bn = slot % NBN;
  gemm0_body<EPI>(bm, bn, bn, Aop, W, bias, Cb, Cf, Xres, Gate, As, Bs);
}

// ---- Attention (single-pass): T = QKr^T @ V (64x64, once per bh), then
//      attn = QKr @ T / 8 for all 1024 rows. Grid = B*H = 192 blocks.
//      Phase 2 uses swapped MFMA operands -> packed bf16x4 column stores.
__global__ __launch_bounds__(256) void attn_kernel(const bf16* __restrict__ QKr,
    const bf16* __restrict__ QKrT, const bf16* __restrict__ VT, bf16* __restrict__ attn) {
  __shared__ float Tp[64][64];
  __shared__ bf16 Tbf[64][72];
  int blk = blockIdx.x;
  int xcd = blk & 7, bhl = blk >> 3;
  int bh = xcd * 24 + bhl;
  int tid = threadIdx.x, wave = tid >> 6, lane = tid & 63;
  int quad = lane >> 4, l16 = lane & 15;
  const bf16* Qt = QKrT + (size_t)bh * (HDIM * NN);
  const bf16* Vt = VT + (size_t)bh * (HDIM * NN);

  floatx4 acc[4][4];
#pragma unroll
  for (int i = 0; i < 4; i++)
#pragma unroll
    for (int j = 0; j < 4; j++)
      acc[i][j] = (floatx4){0.f, 0.f, 0.f, 0.f};

  int kbase = wave * 256;
#pragma unroll
  for (int k0 = 0; k0 < 256; k0 += 32) {
    bf16x8 a[4], b[4];
#pragma unroll
    for (int i = 0; i < 4; i++) a[i] = *(const bf16x8*)&Qt[(size_t)(i * 16 + l16) * NN + kbase + k0 + quad * 8];
#pragma unroll
    for (int i = 0; i < 4; i++) b[i] = *(const bf16x8*)&Vt[(size_t)(i * 16 + l16) * NN + kbase + k0 + quad * 8];
#pragma unroll
    for (int mi = 0; mi < 4; mi++)
#pragma unroll
      for (int ni = 0; ni < 4; ni++)
        acc[mi][ni] = __builtin_amdgcn_mfma_f32_16x16x32_bf16(a[mi], b[ni], acc[mi][ni], 0, 0, 0);
  }
#pragma unroll
  for (int w = 0; w < 4; w++) {
    if (wave == w) {
#pragma unroll
      for (int mi = 0; mi < 4; mi++)
#pragma unroll
        for (int ni = 0; ni < 4; ni++)
#pragma unroll
          for (int r = 0; r < 4; r++) {
            float val = acc[mi][ni][r];
            float* p = &Tp[mi * 16 + quad * 4 + r][ni * 16 + l16];
            if (w == 0) *p = val; else *p += val;
          }
    }
    __syncthreads();
  }
  for (int e = tid; e < 4096; e += 256) {
    int d1 = e >> 6, d2 = e & 63;
    Tbf[d2][d1] = (bf16)(Tp[d1][d2] * 0.125f);
  }
  __syncthreads();

  int b_ = bh / NH, h_ = bh % NH;
  const bf16* Q = QKr + (size_t)(b_ * NN) * DD + h_ * HDIM;
  bf16* Ao = attn + (size_t)(b_ * NN) * DD + h_ * HDIM;
  bf16x8 Bf[4][2];
#pragma unroll
  for (int ni = 0; ni < 4; ni++)
#pragma unroll
    for (int ks = 0; ks < 2; ks++)
      Bf[ni][ks] = *(const bf16x8*)&Tbf[ni * 16 + l16][ks * 32 + quad * 8];

#pragma unroll
  for (int mi = 0; mi < 16; mi++) {
    int nrow = wave * 256 + mi * 16;
    bf16x8 a0 = *(const bf16x8*)&Q[(size_t)(nrow + l16) * DD + quad * 8];
    bf16x8 a1 = *(const bf16x8*)&Q[(size_t)(nrow + l16) * DD + 32 + quad * 8];
    floatx4 o[4];
#pragma unroll
    for (int ni = 0; ni < 4; ni++) o[ni] = (floatx4){0.f, 0.f, 0.f, 0.f};
#pragma unroll
    for (int ni = 0; ni < 4; ni++) {
      o[ni] = __builtin_amdgcn_mfma_f32_16x16x32_bf16(Bf[ni][0], a0, o[ni], 0, 0, 0);
      o[ni] = __builtin_amdgcn_mfma_f32_16x16x32_bf16(Bf[ni][1], a1, o[ni], 0, 0, 0);
    }
#pragma unroll
    for (int ni = 0; ni < 4; ni++) {
      bf16x4 pk;
#pragma unroll
      for (int r = 0; r < 4; r++) pk[r] = (bf16)o[ni][r];
      *(bf16x4*)&Ao[(size_t)(nrow + l16) * DD + ni * 16 + quad * 4] = pk;
    }
  }
}

extern "C" void kernel_launch(void* const* d_in, const int* in_sizes, int n_in,
                              void* d_out, int out_size, void* d_ws, size_t ws_size,
                              hipStream_t stream) {
  const float* x      = (const float*)d_in[0];
  const float* rope   = (const float*)d_in[1];
  const float* ln_w   = (const float*)d_in[2];
  const float* ln_b   = (const float*)d_in[3];
  const float* enc_w  = (const float*)d_in[4];
  const float* enc_b  = (const float*)d_in[5];
  const float* qk_w   = (const float*)d_in[6];
  const float* qk_b   = (const float*)d_in[7];
  const float* v_w    = (const float*)d_in[8];
  const float* v_b    = (const float*)d_in[9];
  const float* out_w  = (const float*)d_in[10];
  const float* out_b  = (const float*)d_in[11];
  const float* gate_w = (const float*)d_in[12];
  const float* gate_b = (const float*)d_in[13];

  char* w = (char*)d_ws;
  const size_t S = (size_t)MTOT * DD * 2;
  bf16* s0 = (bf16*)(w);
  bf16* s1 = (bf16*)(w + S);
  bf16* s2 = (bf16*)(w + 2 * S);
  bf16* s3 = (bf16*)(w + 3 * S);
  bf16* s4 = (bf16*)(w + 4 * S);
  bf16* s5 = (bf16*)(w + 5 * S);
  bf16* Wb = (bf16*)(w + 6 * S);
  float* tabs = (float*)(w + 6 * S + 6 * 1024 * 1024);  // past Wb (5.9 MB)

  bf16* A = s0;
  bf16* L = s1;
  bf16* Gate = s2;
  bf16* QKr = s3;
  bf16* QKrT = s4;
  bf16* VT = s5;
  bf16* attnb = s1;

  prep_kernel<<<dim3(7232), dim3(256), 0, stream>>>(
      x, ln_w, ln_b, A, enc_w, gate_w, qk_w, v_w, out_w, Wb, rope, tabs);

  gemm_kernel<0, 3, 12><<<dim3(768), dim3(512), 0, stream>>>(
      A, Wb, enc_b, gate_b, L, Gate, nullptr, nullptr, nullptr, nullptr, nullptr);
  gemm_kernel<5, 2, 12><<<dim3(768), dim3(512), 0, stream>>>(
      L, Wb + 2 * (size_t)WELEM, qk_b, v_b, QKr, VT, QKrT, nullptr, nullptr, nullptr, tabs);
  attn_kernel<<<dim3(BB * NH), dim3(256), 0, stream>>>(QKr, QKrT, VT, attnb);
  gemm0_kernel<4, 6><<<dim3(384), dim3(256), 0, stream>>>(
      attnb, Wb + 4 * (size_t)WELEM, out_b, nullptr, (float*)d_out, x, Gate);
}